// Round 1
// 356.924 us; speedup vs baseline: 1.0165x; 1.0165x over previous
//
#include <hip/hip_runtime.h>

// Problem constants (from reference): B=4, N=128, M=128, D=256, BD=1024
#define DD   256
#define BD   1024
#define NB   4
#define NN   128
#define MM   128

// Native vector type — __builtin_nontemporal_load requires a native vector,
// not HIP's float4 class type.
typedef float vfloat4 __attribute__((ext_vector_type(4)));

// ---------------------------------------------------------------------------
// Kernel 1: Aw[d,e] = sum_k A[d,e,k] * W[k]
// A is (D, D, BD), k contiguous -> each (d,e) row is 4 KB contiguous.
// One wave per 4 rows, W held in 16 registers/lane (no LDS, no syncthreads).
// 16 nontemporal float4 loads in flight per thread. Coalesced float4 store.
// Grid: 65536 rows / (4 waves * 4 rows) = 4096 blocks x 256 threads.
// At the 256 MB A-read roofline (~40 us at 6.7 TB/s) by construction.
// ---------------------------------------------------------------------------
__global__ __launch_bounds__(256) void reduce_A_kernel(
    const float* __restrict__ A, const float* __restrict__ W,
    float* __restrict__ Aw)
{
    const int t    = threadIdx.x;
    const int lane = t & 63;
    const int wid  = t >> 6;
    const int row0 = blockIdx.x * 16 + wid * 4;   // first of 4 rows for this wave

    const vfloat4* __restrict__ W4 = (const vfloat4*)W;
    const vfloat4 w0 = W4[lane];
    const vfloat4 w1 = W4[lane + 64];
    const vfloat4 w2 = W4[lane + 128];
    const vfloat4 w3 = W4[lane + 192];

    const vfloat4* __restrict__ p = (const vfloat4*)(A + (size_t)row0 * BD) + lane;

    float acc[4];
#pragma unroll
    for (int r = 0; r < 4; ++r) {
        const vfloat4* __restrict__ pr = p + r * 256;
        vfloat4 a0 = __builtin_nontemporal_load(pr);
        vfloat4 a1 = __builtin_nontemporal_load(pr + 64);
        vfloat4 a2 = __builtin_nontemporal_load(pr + 128);
        vfloat4 a3 = __builtin_nontemporal_load(pr + 192);
        acc[r] = a0.x * w0.x + a0.y * w0.y + a0.z * w0.z + a0.w * w0.w
               + a1.x * w1.x + a1.y * w1.y + a1.z * w1.z + a1.w * w1.w
               + a2.x * w2.x + a2.y * w2.y + a2.z * w2.z + a2.w * w2.w
               + a3.x * w3.x + a3.y * w3.y + a3.z * w3.z + a3.w * w3.w;
    }

#pragma unroll
    for (int r = 0; r < 4; ++r) {
#pragma unroll
        for (int off = 32; off > 0; off >>= 1)
            acc[r] += __shfl_down(acc[r], off, 64);
    }

    if (lane == 0) {
        vfloat4 out = {acc[0], acc[1], acc[2], acc[3]};
        ((vfloat4*)Aw)[row0 >> 2] = out;
    }
}

// ---------------------------------------------------------------------------
// Kernel 2: per bn-tile of 2 rows:
//   Z[r][e] = sum_d X[bn0+r][d] * Aw[d][e]        (phase 1)
//   S[bn0+r][m] = sum_e Z[r][e] * Y[b][m][e] + b  (phase 2)
// 256 blocks x 256 threads (was 128 x 4-rows): all 256 CUs now covered,
// 2x the resident waves for the latency-bound phase-1 Aw load chain.
// Aw L2 traffic doubles to 64 MB but Aw (256 KB) is L2/LLC-resident.
// Per-row accumulation order identical to previous version (bitwise-same S).
// ---------------------------------------------------------------------------
__global__ __launch_bounds__(256) void bilinear_fused_kernel(
    const float* __restrict__ X, const float* __restrict__ Y,
    const float* __restrict__ Aw, const float* __restrict__ bias,
    float* __restrict__ S)
{
    const int bn0 = blockIdx.x * 2;   // 2 consecutive (b,n) rows, same b
    const int b   = bn0 >> 7;
    const int t   = threadIdx.x;

    __shared__ float xs[2][DD];
    __shared__ float zs[2][DD];
    __shared__ float partial[2][256];

    xs[0][t] = X[(size_t)bn0 * DD + t];
    xs[1][t] = X[(size_t)(bn0 + 1) * DD + t];
    __syncthreads();

    // Phase 1: e = t; coalesced Aw reads, LDS-broadcast x reads.
    float acc0 = 0.f, acc1 = 0.f;
#pragma unroll 8
    for (int d = 0; d < DD; ++d) {
        float aw = Aw[d * DD + t];
        acc0 += xs[0][d] * aw;
        acc1 += xs[1][d] * aw;
    }
    zs[0][t] = acc0; zs[1][t] = acc1;
    __syncthreads();

    // Phase 2: m = t&127, e-half = t>>7. Y read once, reused for 2 rows.
    const int m  = t & 127;
    const int eh = (t >> 7) << 7;   // 0 or 128
    const float4* __restrict__ Y4 = (const float4*)(Y + ((size_t)b * MM + m) * DD + eh);
    const float4* __restrict__ Z0 = (const float4*)(&zs[0][eh]);
    const float4* __restrict__ Z1 = (const float4*)(&zs[1][eh]);

    float s0 = 0.f, s1 = 0.f;
#pragma unroll 8
    for (int e = 0; e < 32; ++e) {
        float4 y = Y4[e];
        float4 z;
        z = Z0[e]; s0 += z.x * y.x + z.y * y.y + z.z * y.z + z.w * y.w;
        z = Z1[e]; s1 += z.x * y.x + z.y * y.y + z.z * y.z + z.w * y.w;
    }
    partial[0][t] = s0; partial[1][t] = s1;
    __syncthreads();

    if (t < 128) {
        const float b0 = bias[0];
        S[(size_t)bn0 * MM + t]       = partial[0][t] + partial[0][t + 128] + b0;
        S[(size_t)(bn0 + 1) * MM + t] = partial[1][t] + partial[1][t + 128] + b0;
    }
}

extern "C" void kernel_launch(void* const* d_in, const int* in_sizes, int n_in,
                              void* d_out, int out_size, void* d_ws, size_t ws_size,
                              hipStream_t stream) {
    const float* X    = (const float*)d_in[0];  // [4,128,256]
    const float* Y    = (const float*)d_in[1];  // [4,128,256]
    const float* A    = (const float*)d_in[2];  // [256,256,1024]
    const float* W    = (const float*)d_in[3];  // [1,1024]
    const float* bias = (const float*)d_in[4];  // [1]
    float* S  = (float*)d_out;                  // [4,128,128]
    float* Aw = (float*)d_ws;                   // 65536 floats = 256 KB scratch

    reduce_A_kernel<<<dim3(65536 / 16), dim3(256), 0, stream>>>(A, W, Aw);
    bilinear_fused_kernel<<<dim3(NB * NN / 2), dim3(256), 0, stream>>>(X, Y, Aw, bias, S);
}